// Round 1
// baseline (390.999 us; speedup 1.0000x reference)
//
#include <hip/hip_runtime.h>

// Problem: B=2, S=4096, D=512, H=8, DH=64
// inputs: d_in[0]=enc f32 [B,S,D], d_in[1]=causal_mask i32 (tril; ignored),
//         d_in[2..5]=W_Q,W_K,W_V,W_O f32 [D,D]
// out: f32 [B,S,D]
// ws layout (f16): Q[B,H,S,DH] | K[...] | V[...] | att[B,S,D]  -> 4 x 8MB = 32MB

typedef _Float16 f16x8 __attribute__((ext_vector_type(8)));
typedef float f32x4 __attribute__((ext_vector_type(4)));

__device__ inline f32x4 mma16(f16x8 a, f16x8 b, f32x4 c) {
  return __builtin_amdgcn_mfma_f32_16x16x32_f16(a, b, c, 0, 0, 0);
}

// A-frag / row-major B^T-frag: element (lane, j) -> [l&15][4*(l>>4) + (j&3) + 16*(j>>2)]
__device__ inline f16x8 frag_row(const _Float16* base, int stride) {
  const int l = threadIdx.x & 63;
  const _Float16* p = base + (l & 15) * stride + ((l >> 4) << 2);
  union { f16x8 v; uint2 u[2]; } r;
  r.u[0] = *(const uint2*)(p);
  r.u[1] = *(const uint2*)(p + 16);
  return r.v;
}

// B-frag from row-major [k][n] tile: element (lane, j) -> [4*(l>>4) + (j&3) + 16*(j>>2)][l&15]
__device__ inline f16x8 frag_col(const _Float16* base, int stride) {
  const int l = threadIdx.x & 63;
  const _Float16* p = base + (l & 15) + ((l >> 4) << 2) * stride;
  f16x8 v;
#pragma unroll
  for (int j = 0; j < 8; ++j)
    v[j] = p[((j & 3) + ((j >> 2) << 4)) * stride];
  return v;
}

// C = A[8192x512] @ W[512x512]; 64x64 tile per block, 4 waves, BK=64.
// AF16: A is f16 (att) else f32 (enc). OUTMODE 0: f16 [B,H,S,DH]; 1: f32 row-major.
template <bool AF16, int OUTMODE>
__global__ __launch_bounds__(256) void gemm_k(const void* __restrict__ Ap,
                                              const float* __restrict__ Wp,
                                              void* __restrict__ Cp) {
  __shared__ __align__(16) _Float16 Al[64][72];
  __shared__ __align__(16) _Float16 Bl[64][72];
  const int m0 = blockIdx.x * 64, n0 = blockIdx.y * 64;
  const int tid = threadIdx.x, w = tid >> 6, l = tid & 63;
  const int g = l >> 4, li = l & 15;
  const int si = tid >> 2, sj = (tid & 3) * 16;

  f32x4 acc[4];
#pragma unroll
  for (int nt = 0; nt < 4; ++nt) acc[nt] = (f32x4){0.f, 0.f, 0.f, 0.f};

  for (int k0 = 0; k0 < 512; k0 += 64) {
    __syncthreads();
    if constexpr (AF16) {
      const _Float16* Ag = (const _Float16*)Ap + (size_t)(m0 + si) * 512 + k0 + sj;
      *(uint4*)&Al[si][sj] = *(const uint4*)(Ag);
      *(uint4*)&Al[si][sj + 8] = *(const uint4*)(Ag + 8);
    } else {
      const float* Ag = (const float*)Ap + (size_t)(m0 + si) * 512 + k0 + sj;
      union { _Float16 h[16]; uint4 u[2]; } t;
#pragma unroll
      for (int u = 0; u < 16; ++u) t.h[u] = (_Float16)Ag[u];
      *(uint4*)&Al[si][sj] = t.u[0];
      *(uint4*)&Al[si][sj + 8] = t.u[1];
    }
    {
      const float* Bg = Wp + (size_t)(k0 + si) * 512 + n0 + sj;
      union { _Float16 h[16]; uint4 u[2]; } t;
#pragma unroll
      for (int u = 0; u < 16; ++u) t.h[u] = (_Float16)Bg[u];
      *(uint4*)&Bl[si][sj] = t.u[0];
      *(uint4*)&Bl[si][sj + 8] = t.u[1];
    }
    __syncthreads();
#pragma unroll
    for (int ks = 0; ks < 2; ++ks) {
      f16x8 af = frag_row(&Al[w * 16][ks * 32], 72);
#pragma unroll
      for (int nt = 0; nt < 4; ++nt) {
        f16x8 bfr = frag_col(&Bl[ks * 32][nt * 16], 72);
        acc[nt] = mma16(af, bfr, acc[nt]);
      }
    }
  }

#pragma unroll
  for (int nt = 0; nt < 4; ++nt) {
#pragma unroll
    for (int r = 0; r < 4; ++r) {
      const int m = m0 + w * 16 + g * 4 + r;
      const int n = n0 + nt * 16 + li;
      const float v = acc[nt][r];
      if constexpr (OUTMODE == 0) {
        const int b = m >> 12, s = m & 4095, h = n >> 6, dh = n & 63;
        ((_Float16*)Cp)[((((size_t)b << 3) + h) * 4096 + s) * 64 + dh] = (_Float16)v;
      } else {
        ((float*)Cp)[(size_t)m * 512 + n] = v;
      }
    }
  }
}

// Flash attention: per block one (b,h) and 64 Q-rows; 4 waves x 16 rows.
__global__ __launch_bounds__(256) void flash_k(const _Float16* __restrict__ Q,
                                               const _Float16* __restrict__ K,
                                               const _Float16* __restrict__ V,
                                               _Float16* __restrict__ att) {
  __shared__ __align__(16) _Float16 Kl[64][72];
  __shared__ __align__(16) _Float16 Vl[64][72];
  __shared__ __align__(16) _Float16 Pl[4][16][72];

  const int qt = blockIdx.x, bh = blockIdx.y;
  const int b = bh >> 3, h = bh & 7;
  const int q0 = qt * 64;
  const int tid = threadIdx.x, w = tid >> 6, l = tid & 63;
  const int g = l >> 4, li = l & 15;
  const int si = tid >> 2, sq = (tid & 3) * 16;

  const size_t bhoff = (size_t)bh * 4096 * 64;
  const _Float16* Qb = Q + bhoff + (size_t)(q0 + w * 16) * 64;
  f16x8 qf[2];
  qf[0] = frag_row(Qb, 64);
  qf[1] = frag_row(Qb + 32, 64);

  f32x4 o[4];
#pragma unroll
  for (int nt = 0; nt < 4; ++nt) o[nt] = (f32x4){0.f, 0.f, 0.f, 0.f};
  float mrow[4], lrow[4];
#pragma unroll
  for (int r = 0; r < 4; ++r) { mrow[r] = -__builtin_inff(); lrow[r] = 0.f; }

  const _Float16* Kb = K + bhoff;
  const _Float16* Vb = V + bhoff;

  for (int kt = 0; kt <= qt; ++kt) {
    const int k0 = kt * 64;
    __syncthreads();
    {
      const uint4* gk = (const uint4*)(Kb + (size_t)(k0 + si) * 64 + sq);
      const uint4* gv = (const uint4*)(Vb + (size_t)(k0 + si) * 64 + sq);
      *(uint4*)&Kl[si][sq] = gk[0];
      *(uint4*)&Kl[si][sq + 8] = gk[1];
      *(uint4*)&Vl[si][sq] = gv[0];
      *(uint4*)&Vl[si][sq + 8] = gv[1];
    }
    __syncthreads();

    // S = Q K^T
    f32x4 s[4];
#pragma unroll
    for (int nt = 0; nt < 4; ++nt) s[nt] = (f32x4){0.f, 0.f, 0.f, 0.f};
#pragma unroll
    for (int ks = 0; ks < 2; ++ks) {
#pragma unroll
      for (int nt = 0; nt < 4; ++nt)
        s[nt] = mma16(qf[ks], frag_row(&Kl[nt * 16][ks * 32], 72), s[nt]);
    }

    // online softmax (rows = 4*g + r within this wave's 16-row strip)
    const bool diag = (kt == qt);
#pragma unroll
    for (int r = 0; r < 4; ++r) {
      const int qrow = q0 + w * 16 + g * 4 + r;
      float vmax = -__builtin_inff();
#pragma unroll
      for (int nt = 0; nt < 4; ++nt) {
        float sv = s[nt][r] * 0.125f;  // 1/sqrt(64)
        if (diag && (k0 + nt * 16 + li) > qrow) sv = -__builtin_inff();
        s[nt][r] = sv;
        vmax = fmaxf(vmax, sv);
      }
#pragma unroll
      for (int mm = 1; mm < 16; mm <<= 1)
        vmax = fmaxf(vmax, __shfl_xor(vmax, mm, 64));
      const float mn = fmaxf(mrow[r], vmax);
      const float al = __expf(mrow[r] - mn);  // exp(-inf)=0 on first tile
      float rsum = 0.f;
#pragma unroll
      for (int nt = 0; nt < 4; ++nt) {
        const float p = __expf(s[nt][r] - mn);
        s[nt][r] = p;
        rsum += p;
      }
#pragma unroll
      for (int mm = 1; mm < 16; mm <<= 1)
        rsum += __shfl_xor(rsum, mm, 64);
      mrow[r] = mn;
      lrow[r] = lrow[r] * al + rsum;
#pragma unroll
      for (int nt = 0; nt < 4; ++nt) {
        o[nt][r] *= al;
        Pl[w][g * 4 + r][nt * 16 + li] = (_Float16)s[nt][r];
      }
    }

    // O += P V   (per-wave P buffer; DS ops are in-order within a wave)
#pragma unroll
    for (int ks = 0; ks < 2; ++ks) {
      f16x8 pa = frag_row(&Pl[w][0][ks * 32], 72);
#pragma unroll
      for (int nt = 0; nt < 4; ++nt)
        o[nt] = mma16(pa, frag_col(&Vl[ks * 32][nt * 16], 72), o[nt]);
    }
  }

  // epilogue: divide by l, write att[b][s][h*64+dh] (f16)
#pragma unroll
  for (int r = 0; r < 4; ++r) {
    const float inv = 1.f / lrow[r];
    const int srow = q0 + w * 16 + g * 4 + r;
    _Float16* op = att + ((size_t)b * 4096 + srow) * 512 + h * 64;
#pragma unroll
    for (int nt = 0; nt < 4; ++nt)
      op[nt * 16 + li] = (_Float16)(o[nt][r] * inv);
  }
}

extern "C" void kernel_launch(void* const* d_in, const int* in_sizes, int n_in,
                              void* d_out, int out_size, void* d_ws, size_t ws_size,
                              hipStream_t stream) {
  const float* enc = (const float*)d_in[0];
  // d_in[1] = causal mask (tril by construction) — implemented analytically
  const float* WQ = (const float*)d_in[2];
  const float* WK = (const float*)d_in[3];
  const float* WV = (const float*)d_in[4];
  const float* WO = (const float*)d_in[5];
  float* out = (float*)d_out;

  const size_t NELEM = (size_t)2 * 8 * 4096 * 64;  // 4,194,304 per tensor
  _Float16* Qw = (_Float16*)d_ws;
  _Float16* Kw = Qw + NELEM;
  _Float16* Vw = Kw + NELEM;
  _Float16* Aw = Vw + NELEM;  // att [B,S,D] f16; total ws use = 32 MB

  dim3 gg(128, 8), gb(256);
  gemm_k<false, 0><<<gg, gb, 0, stream>>>(enc, WQ, Qw);
  gemm_k<false, 0><<<gg, gb, 0, stream>>>(enc, WK, Kw);
  gemm_k<false, 0><<<gg, gb, 0, stream>>>(enc, WV, Vw);
  flash_k<<<dim3(64, 16), 256, 0, stream>>>(Qw, Kw, Vw, Aw);
  gemm_k<true, 1><<<gg, gb, 0, stream>>>(Aw, WO, out);
}

// Round 2
// 255.907 us; speedup vs baseline: 1.5279x; 1.5279x over previous
//
#include <hip/hip_runtime.h>

// B=2, S=4096, D=512, H=8, DH=64
// ws (f16): Qt[b,h][dh][s] | K[b,h][s][dh] | Vt[b,h][dh][s] | att[b,s,512] | WtQ|WtK|WtV|WtO (each [n][k] 512x512)

typedef _Float16 f16x8 __attribute__((ext_vector_type(8)));
typedef float f32x4 __attribute__((ext_vector_type(4)));

__device__ inline f32x4 mma16(f16x8 a, f16x8 b, f32x4 c) {
  return __builtin_amdgcn_mfma_f32_16x16x32_f16(a, b, c, 0, 0, 0);
}

// fragment with assumed k-map kappa(l,j) = 4*(l>>4) + (j&3) + 16*(j>>2), row = l&15
__device__ inline f16x8 frag_row(const _Float16* base, int stride) {
  const int l = threadIdx.x & 63;
  const _Float16* p = base + (l & 15) * stride + ((l >> 4) << 2);
  union { f16x8 v; uint2 u[2]; } r;
  r.u[0] = *(const uint2*)(p);
  r.u[1] = *(const uint2*)(p + 16);
  return r.v;
}

// 32x32 tiled transpose + f16 convert: T[n][k] = (f16)W[k][n]
__global__ __launch_bounds__(256) void transpose_w_k(const float* __restrict__ W,
                                                     _Float16* __restrict__ T) {
  __shared__ float t[32][33];
  const int k0 = blockIdx.x * 32, n0 = blockIdx.y * 32;
  const int c = threadIdx.x & 31, r8 = threadIdx.x >> 5;
#pragma unroll
  for (int p = 0; p < 4; ++p) {
    const int kr = r8 + p * 8;
    t[c][kr] = W[(size_t)(k0 + kr) * 512 + n0 + c];
  }
  __syncthreads();
#pragma unroll
  for (int p = 0; p < 4; ++p) {
    const int nr = r8 + p * 8;
    T[(size_t)(n0 + nr) * 512 + k0 + c] = (_Float16)t[nr][c];
  }
}

// C = A[8192x512] @ W[512x512], W given transposed f16 (Wt[n][k]).
// OUTMODE 0: f16 [b,h][s][dh]; 1: f32 row-major; 2: f16 transposed [b,h][dh][s]
template <bool AF16, int OUTMODE>
__global__ __launch_bounds__(256) void gemm_k(const void* __restrict__ Ap,
                                              const _Float16* __restrict__ Wt,
                                              void* __restrict__ Cp) {
  __shared__ __align__(16) _Float16 Al[64][72];
  __shared__ __align__(16) _Float16 Bl[64][72];
  const int m0 = blockIdx.x * 64, n0 = blockIdx.y * 64;
  const int tid = threadIdx.x, w = tid >> 6, l = tid & 63;
  const int g = l >> 4, li = l & 15;
  const int si = tid >> 2, sj = (tid & 3) * 16;

  f32x4 acc[4];
#pragma unroll
  for (int nt = 0; nt < 4; ++nt) acc[nt] = (f32x4){0.f, 0.f, 0.f, 0.f};

  for (int k0 = 0; k0 < 512; k0 += 64) {
    __syncthreads();
    if constexpr (AF16) {
      const _Float16* Ag = (const _Float16*)Ap + (size_t)(m0 + si) * 512 + k0 + sj;
      *(uint4*)&Al[si][sj] = *(const uint4*)(Ag);
      *(uint4*)&Al[si][sj + 8] = *(const uint4*)(Ag + 8);
    } else {
      const float* Ag = (const float*)Ap + (size_t)(m0 + si) * 512 + k0 + sj;
      union { _Float16 h[16]; uint4 u[2]; } t;
#pragma unroll
      for (int u = 0; u < 16; ++u) t.h[u] = (_Float16)Ag[u];
      *(uint4*)&Al[si][sj] = t.u[0];
      *(uint4*)&Al[si][sj + 8] = t.u[1];
    }
    {
      const _Float16* Bg = Wt + (size_t)(n0 + si) * 512 + k0 + sj;
      *(uint4*)&Bl[si][sj] = *(const uint4*)(Bg);
      *(uint4*)&Bl[si][sj + 8] = *(const uint4*)(Bg + 8);
    }
    __syncthreads();
#pragma unroll
    for (int ks = 0; ks < 2; ++ks) {
      f16x8 af = frag_row(&Al[w * 16][ks * 32], 72);
#pragma unroll
      for (int nt = 0; nt < 4; ++nt)
        acc[nt] = mma16(af, frag_row(&Bl[nt * 16][ks * 32], 72), acc[nt]);
    }
  }

  if constexpr (OUTMODE == 2) {
    // transpose via LDS bounce, then coalesced write of Ct[n][m]
    __syncthreads();
#pragma unroll
    for (int nt = 0; nt < 4; ++nt)
#pragma unroll
      for (int r = 0; r < 4; ++r)
        Bl[nt * 16 + li][w * 16 + g * 4 + r] = (_Float16)acc[nt][r];
    __syncthreads();
    const int h = n0 >> 6, b = m0 >> 12;
    _Float16* Tp = (_Float16*)Cp + (((size_t)b * 8 + h) * 64 + si) * 4096 + (m0 & 4095) + sj;
    *(uint4*)Tp = *(const uint4*)&Bl[si][sj];
    *(uint4*)(Tp + 8) = *(const uint4*)&Bl[si][sj + 8];
  } else {
#pragma unroll
    for (int nt = 0; nt < 4; ++nt) {
#pragma unroll
      for (int r = 0; r < 4; ++r) {
        const int m = m0 + w * 16 + g * 4 + r;
        const int n = n0 + nt * 16 + li;
        const float v = acc[nt][r];
        if constexpr (OUTMODE == 0) {
          const int b = m >> 12, s = m & 4095, h = n >> 6, dh = n & 63;
          ((_Float16*)Cp)[((((size_t)b << 3) + h) * 4096 + s) * 64 + dh] = (_Float16)v;
        } else {
          ((float*)Cp)[(size_t)m * 512 + n] = v;
        }
      }
    }
  }
}

// Swapped-operand flash attention.
// Per block: one (b,h), 64 q rows; wave w owns q = q0 + w*16 + (l&15).
// S^T = mfma(K_frag, Qt_frag): lane holds P[k = k0+16nt+4g+r][q=li] in s[nt][r].
// PV: O^T = mfma(Vt_frag, P_frag) with P repacked in-register.
__global__ __launch_bounds__(256) void flash_k(const _Float16* __restrict__ Qt,
                                               const _Float16* __restrict__ K,
                                               const _Float16* __restrict__ Vt,
                                               _Float16* __restrict__ att) {
  __shared__ __align__(16) _Float16 Kl[64][72];
  __shared__ __align__(16) _Float16 Vtl[64][72];

  const int qt = 63 - blockIdx.x;  // longest blocks first
  const int bh = blockIdx.y;
  const int b = bh >> 3, h = bh & 7;
  const int q0 = qt * 64;
  const int tid = threadIdx.x, w = tid >> 6, l = tid & 63;
  const int g = l >> 4, li = l & 15;
  const int si = tid >> 2, sj = (tid & 3) * 16;
  const int qg = q0 + w * 16 + li;  // this lane's q row

  const size_t bhoff = (size_t)bh * 4096 * 64;
  const _Float16* Kb = K + bhoff;
  const _Float16* Vtb = Vt + bhoff;  // [dh][s]
  const _Float16* Qtb = Qt + bhoff;  // [dh][s]

  // Q^T B-fragments, loaded once: qB[ks][j] = Q[qg][4g + (j&3) + 16*(j>>2) + 32ks]
  f16x8 qB[2];
#pragma unroll
  for (int ks = 0; ks < 2; ++ks)
#pragma unroll
    for (int j = 0; j < 8; ++j) {
      const int d = g * 4 + (j & 3) + 16 * (j >> 2) + 32 * ks;
      qB[ks][j] = Qtb[(size_t)d * 4096 + qg];
    }

  f32x4 o[4];
#pragma unroll
  for (int nt = 0; nt < 4; ++nt) o[nt] = (f32x4){0.f, 0.f, 0.f, 0.f};
  float mrow = -__builtin_inff(), lrow = 0.f;

  for (int kt = 0; kt <= qt; ++kt) {
    const int k0 = kt * 64;
    __syncthreads();
    {
      const uint4* gk = (const uint4*)(Kb + (size_t)(k0 + si) * 64 + sj);
      *(uint4*)&Kl[si][sj] = gk[0];
      *(uint4*)&Kl[si][sj + 8] = gk[1];
      const uint4* gv = (const uint4*)(Vtb + (size_t)si * 4096 + k0 + sj);
      *(uint4*)&Vtl[si][sj] = gv[0];
      *(uint4*)&Vtl[si][sj + 8] = gv[1];
    }
    __syncthreads();

    // S^T tile: s[nt][r] = S[q=li][k = 16nt + 4g + r]
    f32x4 s[4];
#pragma unroll
    for (int nt = 0; nt < 4; ++nt) s[nt] = (f32x4){0.f, 0.f, 0.f, 0.f};
#pragma unroll
    for (int ks = 0; ks < 2; ++ks)
#pragma unroll
      for (int nt = 0; nt < 4; ++nt)
        s[nt] = mma16(frag_row(&Kl[nt * 16][ks * 32], 72), qB[ks], s[nt]);

    // online softmax, one q-row per lane (replicated over the 4 lane-groups)
    float vmax = -__builtin_inff();
    const bool diag = (kt == qt);
#pragma unroll
    for (int nt = 0; nt < 4; ++nt)
#pragma unroll
      for (int r = 0; r < 4; ++r) {
        float sv = s[nt][r] * 0.125f;  // 1/sqrt(64)
        if (diag && (nt * 16 + g * 4 + r) > (w * 16 + li)) sv = -__builtin_inff();
        s[nt][r] = sv;
        vmax = fmaxf(vmax, sv);
      }
    vmax = fmaxf(vmax, __shfl_xor(vmax, 16, 64));
    vmax = fmaxf(vmax, __shfl_xor(vmax, 32, 64));
    const float mn = fmaxf(mrow, vmax);
    const float al = __expf(mrow - mn);
    float rsum = 0.f;
#pragma unroll
    for (int nt = 0; nt < 4; ++nt)
#pragma unroll
      for (int r = 0; r < 4; ++r) {
        const float p = __expf(s[nt][r] - mn);
        s[nt][r] = p;
        rsum += p;
      }
    rsum += __shfl_xor(rsum, 16, 64);
    rsum += __shfl_xor(rsum, 32, 64);
    mrow = mn;
    lrow = lrow * al + rsum;
#pragma unroll
    for (int nt = 0; nt < 4; ++nt) {
      o[nt][0] *= al; o[nt][1] *= al; o[nt][2] *= al; o[nt][3] *= al;
    }

    // repack P into PV B-fragments (pure in-register)
    f16x8 pb[2];
#pragma unroll
    for (int ks = 0; ks < 2; ++ks)
#pragma unroll
      for (int j = 0; j < 8; ++j)
        pb[ks][j] = (_Float16)s[(j >> 2) + 2 * ks][j & 3];

    // O^T += V^T P^T : o[ntd][r] = O[q=li][d = 16*ntd + 4g + r]
#pragma unroll
    for (int ks = 0; ks < 2; ++ks)
#pragma unroll
      for (int ntd = 0; ntd < 4; ++ntd)
        o[ntd] = mma16(frag_row(&Vtl[ntd * 16][ks * 32], 72), pb[ks], o[ntd]);
  }

  // epilogue: att[b][s=qg][h*64 + d], d = 16*ntd + 4g + r (r consecutive -> 8B stores)
  const float inv = 1.f / lrow;
  _Float16* op = att + ((size_t)b * 4096 + qg) * 512 + h * 64 + g * 4;
#pragma unroll
  for (int ntd = 0; ntd < 4; ++ntd) {
    union { uint2 u; _Float16 h4[4]; } t4;
#pragma unroll
    for (int r = 0; r < 4; ++r) t4.h4[r] = (_Float16)(o[ntd][r] * inv);
    *(uint2*)(op + ntd * 16) = t4.u;
  }
}

extern "C" void kernel_launch(void* const* d_in, const int* in_sizes, int n_in,
                              void* d_out, int out_size, void* d_ws, size_t ws_size,
                              hipStream_t stream) {
  const float* enc = (const float*)d_in[0];
  const float* WQ = (const float*)d_in[2];
  const float* WK = (const float*)d_in[3];
  const float* WV = (const float*)d_in[4];
  const float* WO = (const float*)d_in[5];
  float* out = (float*)d_out;

  const size_t NE = (size_t)2 * 8 * 4096 * 64;  // 4,194,304
  _Float16* Qtw = (_Float16*)d_ws;
  _Float16* Kw = Qtw + NE;
  _Float16* Vtw = Kw + NE;
  _Float16* Aw = Vtw + NE;
  _Float16* WtQ = Aw + NE;
  _Float16* WtK = WtQ + 512 * 512;
  _Float16* WtV = WtK + 512 * 512;
  _Float16* WtO = WtV + 512 * 512;

  dim3 tg(16, 16), tb(256);
  transpose_w_k<<<tg, tb, 0, stream>>>(WQ, WtQ);
  transpose_w_k<<<tg, tb, 0, stream>>>(WK, WtK);
  transpose_w_k<<<tg, tb, 0, stream>>>(WV, WtV);
  transpose_w_k<<<tg, tb, 0, stream>>>(WO, WtO);

  dim3 gg(128, 8), gb(256);
  gemm_k<false, 2><<<gg, gb, 0, stream>>>(enc, WtQ, Qtw);
  gemm_k<false, 0><<<gg, gb, 0, stream>>>(enc, WtK, Kw);
  gemm_k<false, 2><<<gg, gb, 0, stream>>>(enc, WtV, Vtw);
  flash_k<<<dim3(64, 16), 256, 0, stream>>>(Qtw, Kw, Vtw, Aw);
  gemm_k<true, 1><<<gg, gb, 0, stream>>>(Aw, WtO, out);
}